// Round 13
// baseline (223.510 us; speedup 1.0000x reference)
//
#include <hip/hip_runtime.h>
#include <hip/hip_bf16.h>

// B=8, N=256, D=E=G=MID=OUT=128
#define B_ 8
#define N_ 256
#define C_ 128
#define S_ 8
#define STEPB (N_ * C_ * 4)   // 128KB per i-row of one batch
#define SLOT 8704             // 8KB edge + 256B mh + 256B adj

typedef __attribute__((ext_vector_type(4))) float f32x4;
typedef __attribute__((ext_vector_type(8))) short s16x8;

typedef __attribute__((address_space(1))) const void gas_void;
typedef __attribute__((address_space(3))) void las_void;

__device__ __forceinline__ unsigned short f2bf(float f) {
  unsigned int u = __builtin_bit_cast(unsigned int, f);
  u += 0x7FFFu + ((u >> 16) & 1u);   // RNE
  return (unsigned short)(u >> 16);
}

__device__ __forceinline__ unsigned int pk2(float a, float b) {
  __hip_bfloat162 h = __float22bfloat162_rn(make_float2(a, b));
  unsigned int u;
  __builtin_memcpy(&u, &h, 4);
  return u;
}

__device__ __forceinline__ s16x8 cvt8(f32x4 lo, f32x4 hi) {
  union { unsigned int u[4]; s16x8 s; } r;
  r.u[0] = pk2(lo[0], lo[1]);
  r.u[1] = pk2(lo[2], lo[3]);
  r.u[2] = pk2(hi[0], hi[1]);
  r.u[3] = pk2(hi[2], hi[3]);
  return r.s;
}

// ---------- P: ws_c, ws_mh2 (bf16 frag-packed), ws_B, ws_adj ----------
// 1288 blocks x 256 thr; k-split (kh = t>>7) + LDS combine halves the serial
// load-latency chain. 0..511 c (4 rows), 512..1023 mh (4 rows),
// 1024..1031 B-frags (4/block), 1032..1287 adj pack.
__global__ void k_pro(const float* __restrict__ node, const float* __restrict__ hidden,
                      const float* __restrict__ graph, const int* __restrict__ adjm,
                      const float* __restrict__ Wn, const float* __restrict__ bn,
                      const float* __restrict__ Wh, const float* __restrict__ bh,
                      const float* __restrict__ be,
                      const float* __restrict__ Wg, const float* __restrict__ bg,
                      const float* __restrict__ We,
                      float* __restrict__ ws_c, unsigned short* __restrict__ ws_mh2,
                      short* __restrict__ ws_B, unsigned char* __restrict__ ws_adj) {
  int bid = blockIdx.x, t = threadIdx.x;
  if (bid >= 1032) {
    int base = (bid - 1032) * 2048 + t * 8;
    int4 a = *reinterpret_cast<const int4*>(adjm + base);
    int4 c = *reinterpret_cast<const int4*>(adjm + base + 4);
    uint2 v;
    v.x = (unsigned)a.x | ((unsigned)a.y << 8) | ((unsigned)a.z << 16) | ((unsigned)a.w << 24);
    v.y = (unsigned)c.x | ((unsigned)c.y << 8) | ((unsigned)c.z << 16) | ((unsigned)c.w << 24);
    *reinterpret_cast<uint2*>(ws_adj + base) = v;
    return;
  }
  if (bid >= 1024) {
    int f = (bid - 1024) * 4 + (t >> 6);   // 0..31
    int tl = t & 63;
    int kb = f >> 3, nbg = f & 7;
    int lr = tl & 15, lg = tl >> 4;
    s16x8 v;
#pragma unroll
    for (int e = 0; e < 8; ++e)
      v[e] = (short)f2bf(We[(kb * 32 + lg * 8 + e) * C_ + nbg * 16 + lr]);
    *reinterpret_cast<s16x8*>(ws_B + (f * 64 + tl) * 8) = v;
    return;
  }
  bool isc = bid < 512;
  int row0 = (isc ? bid : bid - 512) * 4;   // row = b*N + n
  int col = t & 127, kh = t >> 7;
  const float* src = isc ? node : hidden;
  const float* W   = isc ? Wn : Wh;
  __shared__ float sh[4][C_];
  __shared__ float shp[5][C_];
  {
    int i0 = t, i1 = t + 256;
    sh[i0 >> 7][i0 & 127] = src[(row0 + (i0 >> 7)) * C_ + (i0 & 127)];
    sh[i1 >> 7][i1 & 127] = src[(row0 + (i1 >> 7)) * C_ + (i1 & 127)];
  }
  __syncthreads();
  float g = 0.f;
  float acc[4] = {0.f, 0.f, 0.f, 0.f};
  const float* gr = graph + (row0 >> 8) * C_;
  int kbase = kh * 64;
  for (int k = 0; k < 64; k += 8) {
    float wv[8];
#pragma unroll
    for (int u = 0; u < 8; ++u) wv[u] = W[(kbase + k + u) * C_ + col];
    if (isc) {
      float wgv[8];
#pragma unroll
      for (int u = 0; u < 8; ++u) wgv[u] = Wg[(kbase + k + u) * C_ + col];
#pragma unroll
      for (int u = 0; u < 8; ++u) g += gr[kbase + k + u] * wgv[u];
    }
#pragma unroll
    for (int u = 0; u < 8; ++u)
#pragma unroll
      for (int r = 0; r < 4; ++r) acc[r] += sh[r][kbase + k + u] * wv[u];
  }
  if (kh) {
#pragma unroll
    for (int r = 0; r < 4; ++r) shp[r][col] = acc[r];
    shp[4][col] = g;
  }
  __syncthreads();
  if (!kh) {
#pragma unroll
    for (int r = 0; r < 4; ++r) acc[r] += shp[r][col];
    g += shp[4][col];
    if (isc) {
      float init = bn[col] + be[col] + bg[col] + g;
#pragma unroll
      for (int r = 0; r < 4; ++r) ws_c[(row0 + r) * C_ + col] = acc[r] + init;
    } else {
      int p = (col >> 5) * 32 + (col & 15) * 2 + ((col >> 4) & 1);
#pragma unroll
      for (int r = 0; r < 4; ++r) ws_mh2[(row0 + r) * C_ + p] = f2bf(acc[r] + bh[col]);
    }
  }
}

// ---------- Main: fused edge@We + broadcast-add + masked max ----------
// XCD-locality mapping (R12) + depth-3 pipeline: 4-slot ring, each slot =
// {8KB edge, 256B mh row, 256B adj row} staged together by GLL; issue t+3,
// steady wait vmcnt(8) (2 gens x 4 VMEM in flight), one barrier per step.
// mh/adj GLL4s are duplicated by all 4 waves (identical bytes -> benign race);
// wait-before-barrier gives cross-wave completion of gen T.
__global__ __launch_bounds__(256, 4) void k_main(
    const float* __restrict__ edge, const unsigned char* __restrict__ ws_adj,
    const short* __restrict__ ws_B,
    const float* __restrict__ ws_c, const unsigned short* __restrict__ ws_mh2,
    float* __restrict__ pbuf) {
  __shared__ __align__(16) char smem[4 * SLOT];  // 34816 B
  const int lane = threadIdx.x & 63;
  const int w = threadIdx.x >> 6;
  const int wg = blockIdx.x;
  const int b   = wg & 7;          // XCD-aligned batch
  const int j16 = (wg >> 3) & 15;
  const int s   = wg >> 7;         // i-interleave class: i = s + 8T
  const int j0 = j16 * 16;
  const int n0 = w * 32;
  const int lr = lane & 15;
  const int lg = lane >> 4;

  s16x8 bfrag[4][2];
#pragma unroll
  for (int kb = 0; kb < 4; ++kb)
#pragma unroll
    for (int nb = 0; nb < 2; ++nb)
      bfrag[kb][nb] = *reinterpret_cast<const s16x8*>(
          ws_B + ((kb * 8 + w * 2 + nb) * 64 + lane) * 8);

  float cf[2][4];
#pragma unroll
  for (int nb = 0; nb < 2; ++nb)
#pragma unroll
    for (int r = 0; r < 4; ++r)
      cf[nb][r] = ws_c[(b * N_ + j0 + lg * 4 + r) * C_ + n0 + nb * 16 + lr];

  f32x4 mx[2];
#pragma unroll
  for (int nb = 0; nb < 2; ++nb)
#pragma unroll
    for (int r = 0; r < 4; ++r) mx[nb][r] = -INFINITY;

  const char* gedge = (const char*)(edge + ((size_t)(b * N_ + s) * N_ + j0) * C_);
  const char* gmh   = (const char*)ws_mh2 + (size_t)(b * N_ + s) * 256;
  const char* gadj  = (const char*)(ws_adj + (size_t)b * N_ * N_ + (size_t)s * N_);

  int soff[2];
#pragma unroll
  for (int q = 0; q < 2; ++q) {
    int y = w * 2048 + q * 1024 + lane * 16;
    int row = y >> 9;
    soff[q] = y ^ ((row & 7) << 4);
  }
  const int base0 = lr * 512 + lg * 32;
  const int swz = (lr & 7) << 4;

#define GLL16(GP, LP) __builtin_amdgcn_global_load_lds((gas_void*)(GP), (las_void*)(LP), 16, 0, 0)
#define GLL4(GP, LP)  __builtin_amdgcn_global_load_lds((gas_void*)(GP), (las_void*)(LP), 4, 0, 0)

#define ISSUE(SL, TT) do { \
    char* lb = smem + (SL) * SLOT; \
    const char* gch = gedge + (size_t)(TT) * 8 * STEPB; \
    GLL16(gch + soff[0], lb + w * 2048); \
    GLL16(gch + soff[1], lb + w * 2048 + 1024); \
    GLL4(gmh + (size_t)(TT) * 8 * 256 + lane * 4, lb + 8192); \
    GLL4(gadj + (size_t)(TT) * 8 * N_ + lane * 4, lb + 8448); \
  } while (0)

#define STEP(SL, ISL, WAITN, DOISSUE, TI) do { \
    asm volatile("s_waitcnt vmcnt(" WAITN ")\n\ts_barrier" ::: "memory"); \
    if (DOISSUE) ISSUE(ISL, TI); \
    const char* rb = smem + (SL) * SLOT; \
    s16x8 af[4]; \
    _Pragma("unroll") \
    for (int kb = 0; kb < 4; ++kb) { \
      int a0 = (base0 + kb * 128) ^ swz; \
      f32x4 lo = *reinterpret_cast<const f32x4*>(rb + a0); \
      f32x4 hi = *reinterpret_cast<const f32x4*>(rb + (a0 ^ 16)); \
      af[kb] = cvt8(lo, hi); \
    } \
    unsigned int mw = *reinterpret_cast<const unsigned int*>(rb + 8192 + w * 64 + lr * 4); \
    unsigned int ab = *reinterpret_cast<const unsigned int*>(rb + 8448 + j0 + lg * 4); \
    float mh0 = __builtin_bit_cast(float, mw << 16); \
    float mh1 = __builtin_bit_cast(float, mw & 0xffff0000u); \
    float adjf[4] = {(float)(ab & 0xff), (float)((ab >> 8) & 0xff), \
                     (float)((ab >> 16) & 0xff), (float)(ab >> 24)}; \
    _Pragma("unroll") \
    for (int nb = 0; nb < 2; ++nb) { \
      f32x4 acc; \
      float mhv = nb ? mh1 : mh0; \
      _Pragma("unroll") \
      for (int r = 0; r < 4; ++r) acc[r] = cf[nb][r] + mhv; \
      _Pragma("unroll") \
      for (int kb = 0; kb < 4; ++kb) \
        acc = __builtin_amdgcn_mfma_f32_16x16x32_bf16(af[kb], bfrag[kb][nb], acc, 0, 0, 0); \
      _Pragma("unroll") \
      for (int r = 0; r < 4; ++r) mx[nb][r] = fmaxf(mx[nb][r], adjf[r] * acc[r]); \
    } \
  } while (0)

  // prologue: gens 0,1,2 in flight (4 VMEM each)
  ISSUE(0, 0);
  ISSUE(1, 1);
  ISSUE(2, 2);

  // steady: T = 0..27 (issue gens 3..30), T=28 issues 31, drain 29..31
  for (int o = 0; o < 7; ++o) {
    STEP(0, 3, "8", 1, 4 * o + 3);
    STEP(1, 0, "8", 1, 4 * o + 4);
    STEP(2, 1, "8", 1, 4 * o + 5);
    STEP(3, 2, "8", 1, 4 * o + 6);
  }
  STEP(0, 3, "8", 1, 31);
  STEP(1, 0, "8", 0, 0);
  STEP(2, 1, "4", 0, 0);
  STEP(3, 2, "0", 0, 0);

#undef STEP
#undef ISSUE
#undef GLL16
#undef GLL4

  float* prow = pbuf + (((size_t)s * B_ + b) * N_ + j0 + lg * 4) * C_ + n0 + lr;
#pragma unroll
  for (int nb = 0; nb < 2; ++nb)
#pragma unroll
    for (int r = 0; r < 4; ++r)
      prow[r * C_ + nb * 16] = mx[nb][r];
}

// ---------- Epilogue: S-max + node@Wo1 + hidden@Wo2 + msgs@Wo3 ----------
// 1024 blocks x 256 thr; 2 rows/block, k-split (kh) + LDS combine.
__global__ void k_epi(const float* __restrict__ node, const float* __restrict__ hidden,
                      const float* __restrict__ Wo1, const float* __restrict__ bo1,
                      const float* __restrict__ Wo2, const float* __restrict__ bo2,
                      const float* __restrict__ Wo3, const float* __restrict__ bo3,
                      const float* __restrict__ pbuf, float* __restrict__ out) {
  int row0 = blockIdx.x * 2;
  int t = threadIdx.x;
  int col = t & 127, kh = t >> 7;
  __shared__ float shn[2][C_], shh[2][C_], shm[2][C_], shp[2][C_];
  {
    int r = t >> 7, c = t & 127;
    shn[r][c] = node[(row0 + r) * C_ + c];
    shh[r][c] = hidden[(row0 + r) * C_ + c];
    float mv = -INFINITY;
#pragma unroll
    for (int s = 0; s < S_; ++s)
      mv = fmaxf(mv, pbuf[((size_t)s * (B_ * N_) + row0 + r) * C_ + c]);
    shm[r][c] = mv;
  }
  __syncthreads();
  float acc[2] = {0.f, 0.f};
  int kbase = kh * 64;
  for (int k = 0; k < 64; k += 8) {
    float wv1[8], wv2[8], wv3[8];
#pragma unroll
    for (int u = 0; u < 8; ++u) {
      wv1[u] = Wo1[(kbase + k + u) * C_ + col];
      wv2[u] = Wo2[(kbase + k + u) * C_ + col];
      wv3[u] = Wo3[(kbase + k + u) * C_ + col];
    }
#pragma unroll
    for (int u = 0; u < 8; ++u)
#pragma unroll
      for (int r = 0; r < 2; ++r)
        acc[r] += shn[r][kbase + k + u] * wv1[u] + shh[r][kbase + k + u] * wv2[u]
                + shm[r][kbase + k + u] * wv3[u];
  }
  if (kh) { shp[0][col] = acc[0]; shp[1][col] = acc[1]; }
  __syncthreads();
  if (!kh) {
    float init = bo1[col] + bo2[col] + bo3[col];
#pragma unroll
    for (int r = 0; r < 2; ++r)
      out[(row0 + r) * C_ + col] = acc[r] + shp[r][col] + init;
  }
}

extern "C" void kernel_launch(void* const* d_in, const int* in_sizes, int n_in,
                              void* d_out, int out_size, void* d_ws, size_t ws_size,
                              hipStream_t stream) {
  const float* node   = (const float*)d_in[0];
  const float* edge   = (const float*)d_in[1];
  const float* graph  = (const float*)d_in[2];
  const int*   adjm   = (const int*)d_in[3];
  const float* hidden = (const float*)d_in[4];
  const float* Wn = (const float*)d_in[5];  const float* bn = (const float*)d_in[6];
  const float* Wh = (const float*)d_in[7];  const float* bh = (const float*)d_in[8];
  const float* We = (const float*)d_in[9];  const float* be = (const float*)d_in[10];
  const float* Wg = (const float*)d_in[11]; const float* bg = (const float*)d_in[12];
  const float* Wo1 = (const float*)d_in[13]; const float* bo1 = (const float*)d_in[14];
  const float* Wo2 = (const float*)d_in[15]; const float* bo2 = (const float*)d_in[16];
  const float* Wo3 = (const float*)d_in[17]; const float* bo3 = (const float*)d_in[18];
  float* out = (float*)d_out;

  char* ws = (char*)d_ws;
  float*          ws_c   = (float*)ws;                            // 1 MB
  unsigned short* ws_mh2 = (unsigned short*)(ws + (1u << 20));    // 512 KB (bf16)
  short*          ws_B   = (short*)(ws + 1572864u);               // 32 KB
  unsigned char*  ws_adj = (unsigned char*)(ws + 1835008u);       // 512 KB
  float*          pbuf   = (float*)(ws + (4u << 20));             // 8 MB partials

  k_pro<<<1288, 256, 0, stream>>>(node, hidden, graph, adjm, Wn, bn, Wh, bh, be,
                                  Wg, bg, We, ws_c, ws_mh2, ws_B, ws_adj);
  k_main<<<1024, 256, 0, stream>>>(edge, ws_adj, ws_B, ws_c, ws_mh2, pbuf);
  k_epi<<<1024, 256, 0, stream>>>(node, hidden, Wo1, bo1, Wo2, bo2, Wo3, bo3,
                                  pbuf, out);
}

// Round 14
// 85.266 us; speedup vs baseline: 2.6213x; 2.6213x over previous
//
#include <hip/hip_runtime.h>
#include <hip/hip_bf16.h>

// B=8, N=256, D=E=G=MID=OUT=128
#define B_ 8
#define N_ 256
#define C_ 128
#define S_ 8
#define STEPB (N_ * C_ * 4)   // 128KB per i-row of one batch
#define SLOT 8704             // 8KB edge + 256B mh + 256B adj

typedef __attribute__((ext_vector_type(4))) float f32x4;
typedef __attribute__((ext_vector_type(8))) short s16x8;

typedef __attribute__((address_space(1))) const void gas_void;
typedef __attribute__((address_space(3))) void las_void;

__device__ __forceinline__ unsigned short f2bf(float f) {
  unsigned int u = __builtin_bit_cast(unsigned int, f);
  u += 0x7FFFu + ((u >> 16) & 1u);   // RNE
  return (unsigned short)(u >> 16);
}

__device__ __forceinline__ unsigned int pk2(float a, float b) {
  __hip_bfloat162 h = __float22bfloat162_rn(make_float2(a, b));
  unsigned int u;
  __builtin_memcpy(&u, &h, 4);
  return u;
}

__device__ __forceinline__ s16x8 cvt8(f32x4 lo, f32x4 hi) {
  union { unsigned int u[4]; s16x8 s; } r;
  r.u[0] = pk2(lo[0], lo[1]);
  r.u[1] = pk2(lo[2], lo[3]);
  r.u[2] = pk2(hi[0], hi[1]);
  r.u[3] = pk2(hi[2], hi[3]);
  return r.s;
}

// ---------- P: ws_c, ws_mh2 (bf16 frag-packed), ws_B, ws_adj ----------
// REVERTED to the R12-proven version (measured 8.6us): 1056 blocks x 128 thr.
// 0..255 -> c (8 rows), 256..511 -> mh2 (8 rows), 512..543 -> B-frags, 544+ -> adj pack
__global__ void k_pro(const float* __restrict__ node, const float* __restrict__ hidden,
                      const float* __restrict__ graph, const int* __restrict__ adjm,
                      const float* __restrict__ Wn, const float* __restrict__ bn,
                      const float* __restrict__ Wh, const float* __restrict__ bh,
                      const float* __restrict__ be,
                      const float* __restrict__ Wg, const float* __restrict__ bg,
                      const float* __restrict__ We,
                      float* __restrict__ ws_c, unsigned short* __restrict__ ws_mh2,
                      short* __restrict__ ws_B, unsigned char* __restrict__ ws_adj) {
  int bid = blockIdx.x, t = threadIdx.x;
  if (bid >= 544) {
    int base = (bid - 544) * 1024 + t * 8;
    int4 a = *reinterpret_cast<const int4*>(adjm + base);
    int4 c = *reinterpret_cast<const int4*>(adjm + base + 4);
    uint2 v;
    v.x = (unsigned)a.x | ((unsigned)a.y << 8) | ((unsigned)a.z << 16) | ((unsigned)a.w << 24);
    v.y = (unsigned)c.x | ((unsigned)c.y << 8) | ((unsigned)c.z << 16) | ((unsigned)c.w << 24);
    *reinterpret_cast<uint2*>(ws_adj + base) = v;
    return;
  }
  if (bid >= 512) {
    int f = bid - 512;                 // 0..31
    if (t < 64) {
      int kb = f >> 3, nbg = f & 7;
      int lr = t & 15, lg = t >> 4;
      s16x8 v;
#pragma unroll
      for (int e = 0; e < 8; ++e)
        v[e] = (short)f2bf(We[(kb * 32 + lg * 8 + e) * C_ + nbg * 16 + lr]);
      *reinterpret_cast<s16x8*>(ws_B + (f * 64 + t) * 8) = v;
    }
    return;
  }
  bool isc = bid < 256;
  int row0 = (isc ? bid : bid - 256) * 8;
  const float* src = isc ? node : hidden;
  const float* W   = isc ? Wn : Wh;
  __shared__ float sh[8][C_];
#pragma unroll
  for (int r = 0; r < 8; ++r) sh[r][t] = src[(row0 + r) * C_ + t];
  __syncthreads();
  float g = 0.f;
  float acc[8];
#pragma unroll
  for (int r = 0; r < 8; ++r) acc[r] = 0.f;
  const float* gr = graph + (row0 >> 8) * C_;
  for (int k = 0; k < C_; k += 8) {
    float wv[8];
#pragma unroll
    for (int u = 0; u < 8; ++u) wv[u] = W[(k + u) * C_ + t];
    if (isc) {
      float wgv[8];
#pragma unroll
      for (int u = 0; u < 8; ++u) wgv[u] = Wg[(k + u) * C_ + t];
#pragma unroll
      for (int u = 0; u < 8; ++u) g += gr[k + u] * wgv[u];
    }
#pragma unroll
    for (int u = 0; u < 8; ++u)
#pragma unroll
      for (int r = 0; r < 8; ++r) acc[r] += sh[r][k + u] * wv[u];
  }
  if (isc) {
    float init = bn[t] + be[t] + bg[t] + g;
#pragma unroll
    for (int r = 0; r < 8; ++r) ws_c[(row0 + r) * C_ + t] = acc[r] + init;
  } else {
    float init = bh[t];
    int p = (t >> 5) * 32 + (t & 15) * 2 + ((t >> 4) & 1);
#pragma unroll
    for (int r = 0; r < 8; ++r) ws_mh2[(row0 + r) * C_ + p] = f2bf(acc[r] + init);
  }
}

// ---------- Main: fused edge@We + broadcast-add + masked max ----------
// R13's k_main (kept): XCD-locality mapping + 4-slot ring, slot = {8KB edge,
// 256B mh, 256B adj} staged together, issue t+3, steady vmcnt(8), one barrier
// per step. Only change: pbuf is now bf16 (halved partial-write traffic).
__global__ __launch_bounds__(256, 4) void k_main(
    const float* __restrict__ edge, const unsigned char* __restrict__ ws_adj,
    const short* __restrict__ ws_B,
    const float* __restrict__ ws_c, const unsigned short* __restrict__ ws_mh2,
    unsigned short* __restrict__ pbuf) {
  __shared__ __align__(16) char smem[4 * SLOT];  // 34816 B
  const int lane = threadIdx.x & 63;
  const int w = threadIdx.x >> 6;
  const int wg = blockIdx.x;
  const int b   = wg & 7;          // XCD-aligned batch
  const int j16 = (wg >> 3) & 15;
  const int s   = wg >> 7;         // i-interleave class: i = s + 8T
  const int j0 = j16 * 16;
  const int n0 = w * 32;
  const int lr = lane & 15;
  const int lg = lane >> 4;

  s16x8 bfrag[4][2];
#pragma unroll
  for (int kb = 0; kb < 4; ++kb)
#pragma unroll
    for (int nb = 0; nb < 2; ++nb)
      bfrag[kb][nb] = *reinterpret_cast<const s16x8*>(
          ws_B + ((kb * 8 + w * 2 + nb) * 64 + lane) * 8);

  float cf[2][4];
#pragma unroll
  for (int nb = 0; nb < 2; ++nb)
#pragma unroll
    for (int r = 0; r < 4; ++r)
      cf[nb][r] = ws_c[(b * N_ + j0 + lg * 4 + r) * C_ + n0 + nb * 16 + lr];

  f32x4 mx[2];
#pragma unroll
  for (int nb = 0; nb < 2; ++nb)
#pragma unroll
    for (int r = 0; r < 4; ++r) mx[nb][r] = -INFINITY;

  const char* gedge = (const char*)(edge + ((size_t)(b * N_ + s) * N_ + j0) * C_);
  const char* gmh   = (const char*)ws_mh2 + (size_t)(b * N_ + s) * 256;
  const char* gadj  = (const char*)(ws_adj + (size_t)b * N_ * N_ + (size_t)s * N_);

  int soff[2];
#pragma unroll
  for (int q = 0; q < 2; ++q) {
    int y = w * 2048 + q * 1024 + lane * 16;
    int row = y >> 9;
    soff[q] = y ^ ((row & 7) << 4);
  }
  const int base0 = lr * 512 + lg * 32;
  const int swz = (lr & 7) << 4;

#define GLL16(GP, LP) __builtin_amdgcn_global_load_lds((gas_void*)(GP), (las_void*)(LP), 16, 0, 0)
#define GLL4(GP, LP)  __builtin_amdgcn_global_load_lds((gas_void*)(GP), (las_void*)(LP), 4, 0, 0)

#define ISSUE(SL, TT) do { \
    char* lb = smem + (SL) * SLOT; \
    const char* gch = gedge + (size_t)(TT) * 8 * STEPB; \
    GLL16(gch + soff[0], lb + w * 2048); \
    GLL16(gch + soff[1], lb + w * 2048 + 1024); \
    GLL4(gmh + (size_t)(TT) * 8 * 256 + lane * 4, lb + 8192); \
    GLL4(gadj + (size_t)(TT) * 8 * N_ + lane * 4, lb + 8448); \
  } while (0)

#define STEP(SL, ISL, WAITN, DOISSUE, TI) do { \
    asm volatile("s_waitcnt vmcnt(" WAITN ")\n\ts_barrier" ::: "memory"); \
    if (DOISSUE) ISSUE(ISL, TI); \
    const char* rb = smem + (SL) * SLOT; \
    s16x8 af[4]; \
    _Pragma("unroll") \
    for (int kb = 0; kb < 4; ++kb) { \
      int a0 = (base0 + kb * 128) ^ swz; \
      f32x4 lo = *reinterpret_cast<const f32x4*>(rb + a0); \
      f32x4 hi = *reinterpret_cast<const f32x4*>(rb + (a0 ^ 16)); \
      af[kb] = cvt8(lo, hi); \
    } \
    unsigned int mw = *reinterpret_cast<const unsigned int*>(rb + 8192 + w * 64 + lr * 4); \
    unsigned int ab = *reinterpret_cast<const unsigned int*>(rb + 8448 + j0 + lg * 4); \
    float mh0 = __builtin_bit_cast(float, mw << 16); \
    float mh1 = __builtin_bit_cast(float, mw & 0xffff0000u); \
    float adjf[4] = {(float)(ab & 0xff), (float)((ab >> 8) & 0xff), \
                     (float)((ab >> 16) & 0xff), (float)(ab >> 24)}; \
    _Pragma("unroll") \
    for (int nb = 0; nb < 2; ++nb) { \
      f32x4 acc; \
      float mhv = nb ? mh1 : mh0; \
      _Pragma("unroll") \
      for (int r = 0; r < 4; ++r) acc[r] = cf[nb][r] + mhv; \
      _Pragma("unroll") \
      for (int kb = 0; kb < 4; ++kb) \
        acc = __builtin_amdgcn_mfma_f32_16x16x32_bf16(af[kb], bfrag[kb][nb], acc, 0, 0, 0); \
      _Pragma("unroll") \
      for (int r = 0; r < 4; ++r) mx[nb][r] = fmaxf(mx[nb][r], adjf[r] * acc[r]); \
    } \
  } while (0)

  // prologue: gens 0,1,2 in flight (4 VMEM each)
  ISSUE(0, 0);
  ISSUE(1, 1);
  ISSUE(2, 2);

  // steady: T = 0..27 (issue gens 3..30), T=28 issues 31, drain 29..31
  for (int o = 0; o < 7; ++o) {
    STEP(0, 3, "8", 1, 4 * o + 3);
    STEP(1, 0, "8", 1, 4 * o + 4);
    STEP(2, 1, "8", 1, 4 * o + 5);
    STEP(3, 2, "8", 1, 4 * o + 6);
  }
  STEP(0, 3, "8", 1, 31);
  STEP(1, 0, "8", 0, 0);
  STEP(2, 1, "4", 0, 0);
  STEP(3, 2, "0", 0, 0);

#undef STEP
#undef ISSUE
#undef GLL16
#undef GLL4

  unsigned short* prow = pbuf + (((size_t)s * B_ + b) * N_ + j0 + lg * 4) * C_ + n0 + lr;
#pragma unroll
  for (int nb = 0; nb < 2; ++nb)
#pragma unroll
    for (int r = 0; r < 4; ++r)
      prow[r * C_ + nb * 16] = f2bf(mx[nb][r]);
}

// ---------- Epilogue: S-max + node@Wo1 + hidden@Wo2 + msgs@Wo3 ----------
// REVERTED to R12-proven version (8.7us): 512 blocks x 256 thr, 4 rows/block,
// thread (col, half) does 2 rows. Only change: pbuf is bf16.
__global__ void k_epi(const float* __restrict__ node, const float* __restrict__ hidden,
                      const float* __restrict__ Wo1, const float* __restrict__ bo1,
                      const float* __restrict__ Wo2, const float* __restrict__ bo2,
                      const float* __restrict__ Wo3, const float* __restrict__ bo3,
                      const unsigned short* __restrict__ pbuf, float* __restrict__ out) {
  int row0 = blockIdx.x * 4;
  int col = threadIdx.x & 127;
  int half = threadIdx.x >> 7;
  __shared__ float shn[4][C_], shh[4][C_], shm[4][C_];
#pragma unroll
  for (int r = 0; r < 2; ++r) {
    int rr = half * 2 + r;
    shn[rr][col] = node[(row0 + rr) * C_ + col];
    shh[rr][col] = hidden[(row0 + rr) * C_ + col];
    float mv = -INFINITY;
#pragma unroll
    for (int s = 0; s < S_; ++s) {
      unsigned int u = pbuf[((size_t)s * (B_ * N_) + row0 + rr) * C_ + col];
      mv = fmaxf(mv, __builtin_bit_cast(float, u << 16));
    }
    shm[rr][col] = mv;
  }
  __syncthreads();
  float init = bo1[col] + bo2[col] + bo3[col];
  float acc[2];
  acc[0] = init; acc[1] = init;
  for (int k = 0; k < C_; k += 8) {
    float wv1[8], wv2[8], wv3[8];
#pragma unroll
    for (int u = 0; u < 8; ++u) {
      wv1[u] = Wo1[(k + u) * C_ + col];
      wv2[u] = Wo2[(k + u) * C_ + col];
      wv3[u] = Wo3[(k + u) * C_ + col];
    }
#pragma unroll
    for (int u = 0; u < 8; ++u)
#pragma unroll
      for (int r = 0; r < 2; ++r) {
        int rr = half * 2 + r;
        acc[r] += shn[rr][k + u] * wv1[u] + shh[rr][k + u] * wv2[u] + shm[rr][k + u] * wv3[u];
      }
  }
#pragma unroll
  for (int r = 0; r < 2; ++r)
    out[(row0 + half * 2 + r) * C_ + col] = acc[r];
}

extern "C" void kernel_launch(void* const* d_in, const int* in_sizes, int n_in,
                              void* d_out, int out_size, void* d_ws, size_t ws_size,
                              hipStream_t stream) {
  const float* node   = (const float*)d_in[0];
  const float* edge   = (const float*)d_in[1];
  const float* graph  = (const float*)d_in[2];
  const int*   adjm   = (const int*)d_in[3];
  const float* hidden = (const float*)d_in[4];
  const float* Wn = (const float*)d_in[5];  const float* bn = (const float*)d_in[6];
  const float* Wh = (const float*)d_in[7];  const float* bh = (const float*)d_in[8];
  const float* We = (const float*)d_in[9];  const float* be = (const float*)d_in[10];
  const float* Wg = (const float*)d_in[11]; const float* bg = (const float*)d_in[12];
  const float* Wo1 = (const float*)d_in[13]; const float* bo1 = (const float*)d_in[14];
  const float* Wo2 = (const float*)d_in[15]; const float* bo2 = (const float*)d_in[16];
  const float* Wo3 = (const float*)d_in[17]; const float* bo3 = (const float*)d_in[18];
  float* out = (float*)d_out;

  char* ws = (char*)d_ws;
  float*          ws_c   = (float*)ws;                            // 1 MB
  unsigned short* ws_mh2 = (unsigned short*)(ws + (1u << 20));    // 512 KB (bf16)
  short*          ws_B   = (short*)(ws + 1572864u);               // 32 KB
  unsigned char*  ws_adj = (unsigned char*)(ws + 1835008u);       // 512 KB
  unsigned short* pbuf   = (unsigned short*)(ws + (4u << 20));    // 4 MB partials (bf16)

  k_pro<<<1056, 128, 0, stream>>>(node, hidden, graph, adjm, Wn, bn, Wh, bh, be,
                                  Wg, bg, We, ws_c, ws_mh2, ws_B, ws_adj);
  k_main<<<1024, 256, 0, stream>>>(edge, ws_adj, ws_B, ws_c, ws_mh2, pbuf);
  k_epi<<<512, 256, 0, stream>>>(node, hidden, Wo1, bo1, Wo2, bo2, Wo3, bo3,
                                 pbuf, out);
}